// Round 10
// baseline (1407.295 us; speedup 1.0000x reference)
//
#include <hip/hip_runtime.h>

#define NN 100000
#define NC 16
#define NE 3200000
#define NLAYERS 4
#define ALPHA_C 0.5f

#define BSHIFT 7
#define BMASK 127
#define NODES_PER_BUK 128
#define NBUK 782            // ceil(NN / 128)
#define EPB 12544           // edges per block -> exactly 256 blocks
#define NBLK 256

typedef __attribute__((ext_vector_type(4))) _Float16 half4;

// ============ build phase (LDS atomics only) ============

__global__ __launch_bounds__(1024) void bucket_count(const int* __restrict__ dst,
                                                     int* __restrict__ counts) {
    __shared__ int h[NBUK];
    for (int i = threadIdx.x; i < NBUK; i += 1024) h[i] = 0;
    __syncthreads();
    int base = blockIdx.x * EPB;
    int nedge = min(EPB, NE - base);
    for (int i = threadIdx.x; i < nedge; i += 1024)
        atomicAdd(&h[dst[base + i] >> BSHIFT], 1);
    __syncthreads();
    for (int i = threadIdx.x; i < NBUK; i += 1024)
        counts[i * NBLK + blockIdx.x] = h[i];   // bucket-major for the scan
}

// Exclusive scan, 1024 elements per block (256 threads x 4 elems).
__global__ void scanA(int* __restrict__ data, int* __restrict__ blockSums, int n) {
    __shared__ int lds[256];
    int base = blockIdx.x * 1024 + threadIdx.x * 4;
    int v[4] = {0, 0, 0, 0};
#pragma unroll
    for (int i = 0; i < 4; ++i) { int idx = base + i; if (idx < n) v[i] = data[idx]; }
    int tsum = v[0] + v[1] + v[2] + v[3];
    lds[threadIdx.x] = tsum;
    __syncthreads();
    for (int off = 1; off < 256; off <<= 1) {
        int t = (threadIdx.x >= off) ? lds[threadIdx.x - off] : 0;
        __syncthreads();
        lds[threadIdx.x] += t;
        __syncthreads();
    }
    if (threadIdx.x == 255) blockSums[blockIdx.x] = lds[255];
    int run = lds[threadIdx.x] - tsum;
#pragma unroll
    for (int i = 0; i < 4; ++i) {
        int idx = base + i;
        if (idx < n) { int old = v[i]; data[idx] = run; run += old; }
    }
}

__global__ void scanB(int* __restrict__ blockSums, int nb) {
    __shared__ int lds[1024];
    int t = threadIdx.x;
    lds[t] = (t < nb) ? blockSums[t] : 0;
    __syncthreads();
    for (int off = 1; off < 1024; off <<= 1) {
        int v = (t >= off) ? lds[t - off] : 0;
        __syncthreads();
        lds[t] += v;
        __syncthreads();
    }
    if (t < nb) blockSums[t] = (t == 0) ? 0 : lds[t - 1];
}

__global__ void scanC(int* __restrict__ data, const int* __restrict__ blockSums, int n) {
    int idx = blockIdx.x * blockDim.x + threadIdx.x;
    if (idx < n) data[idx] += blockSums[idx >> 10];
    if (idx == 0) data[n] = NE;
}

// LDS-staged scatter: histogram -> LDS scan -> LDS placement (bucket-ordered)
// -> linear coalesced write-out. rec.x = src | (local_dst<<17), rec.y = w bits.
__global__ __launch_bounds__(1024) void bucket_scatter(
        const int* __restrict__ src, const int* __restrict__ dst,
        const float* __restrict__ ew, const float* __restrict__ W,
        const int* __restrict__ scanned, int2* __restrict__ recs) {
    __shared__ int2 lrec[EPB];               // 100352 B
    __shared__ unsigned short lbid[EPB];     // 25088 B
    __shared__ int h[NBUK];
    __shared__ int lbase[NBUK];
    __shared__ int delta[NBUK];
    __shared__ int sc[1024];
    int t = threadIdx.x;
    int blk = blockIdx.x;
    for (int i = t; i < NBUK; i += 1024) h[i] = 0;
    __syncthreads();
    int base = blk * EPB;
    int nedge = min(EPB, NE - base);
    for (int i = t; i < nedge; i += 1024)
        atomicAdd(&h[dst[base + i] >> BSHIFT], 1);
    __syncthreads();
    // exclusive LDS scan of h -> lbase; delta = global base - local base
    sc[t] = (t < NBUK) ? h[t] : 0;
    __syncthreads();
    for (int off = 1; off < 1024; off <<= 1) {
        int v = (t >= off) ? sc[t - off] : 0;
        __syncthreads();
        sc[t] += v;
        __syncthreads();
    }
    if (t < NBUK) {
        int excl = sc[t] - h[t];
        lbase[t] = excl;
        delta[t] = scanned[t * NBLK + blk] - excl;
        h[t] = 0;
    }
    __syncthreads();
    // placement into LDS, bucket-ordered
    for (int i = t; i < nedge; i += 1024) {
        int e = base + i;
        int d = dst[e];
        int s = src[e];
        float w = ew[e] * W[s];
        int b = d >> BSHIFT;
        int r = atomicAdd(&h[b], 1);
        int slot = lbase[b] + r;
        lrec[slot] = make_int2(s | ((d & BMASK) << 17), __float_as_int(w));
        lbid[slot] = (unsigned short)b;
    }
    __syncthreads();
    // coalesced write-out: consecutive threads -> consecutive addresses per run
    for (int i = t; i < nedge; i += 1024) {
        int b = lbid[i];
        recs[i + delta[b]] = lrec[i];
    }
}

// ============ fp32 -> fp16 conversion (once) ============
__global__ void f32_to_f16(const float* __restrict__ in, _Float16* __restrict__ out) {
    int i = blockIdx.x * blockDim.x + threadIdx.x;
    int base = i * 4;
    if (base < NN * NC) {
        float4 v = *reinterpret_cast<const float4*>(in + base);
        half4 o;
        o.x = (_Float16)v.x; o.y = (_Float16)v.y;
        o.z = (_Float16)v.z; o.w = (_Float16)v.w;
        *reinterpret_cast<half4*>(out + base) = o;
    }
}

// ============ per-layer gather: edge-parallel, LDS accumulate ============
// One block per bucket (128 dsts). 4 lanes per edge (lane q owns classes
// [4q,4q+4)); independent edge iterations -> deep MLP, no serial chains.
// LDS atomic adds into acc[128][16]; fused deg^2-blend + rownorm epilogue.
template<bool LAST>
__global__ __launch_bounds__(256) void gather_lds(
        const _Float16* __restrict__ h, const int2* __restrict__ recs,
        const int* __restrict__ scanned, const float* __restrict__ degree,
        _Float16* __restrict__ hout16, float* __restrict__ hout32) {
    __shared__ float acc[NODES_PER_BUK * NC];   // 8 KB
    int b = blockIdx.x;
    int t = threadIdx.x;
    for (int i = t; i < NODES_PER_BUK * NC; i += 256) acc[i] = 0.f;
    __syncthreads();
    int beg = scanned[b * NBLK];
    int end = (b == NBUK - 1) ? NE : scanned[(b + 1) * NBLK];
    int q4 = (t & 3) * 4;
    for (int i = beg + (t >> 2); i < end; i += 64) {
        long long v = __builtin_nontemporal_load((const long long*)(recs + i));
        int s  = (int)v & 0x1FFFF;
        int ld = ((int)v >> 17) & BMASK;
        float w = __int_as_float((int)(v >> 32));
        const half4 hv = *reinterpret_cast<const half4*>(h + (size_t)s * NC + q4);
        float* a = acc + ld * NC + q4;
        unsafeAtomicAdd(a + 0, (float)hv[0] * w);
        unsafeAtomicAdd(a + 1, (float)hv[1] * w);
        unsafeAtomicAdd(a + 2, (float)hv[2] * w);
        unsafeAtomicAdd(a + 3, (float)hv[3] * w);
    }
    __syncthreads();
    // epilogue: 2 threads per node, 8 classes each
    int nl = t >> 1;
    int g = b * NODES_PER_BUK + nl;
    if (g >= NN) return;
    int c8 = (t & 1) * 8;
    float deg = degree[g];
    float d2 = deg * deg;
    const half4 hs0 = *reinterpret_cast<const half4*>(h + (size_t)g * NC + c8);
    const half4 hs1 = *reinterpret_cast<const half4*>(h + (size_t)g * NC + c8 + 4);
    float v[8];
    float s8 = 0.f;
#pragma unroll
    for (int j = 0; j < 4; ++j) {
        v[j]     = ALPHA_C * (float)hs0[j] + (1.f - ALPHA_C) * d2 * acc[nl * NC + c8 + j];
        v[j + 4] = ALPHA_C * (float)hs1[j] + (1.f - ALPHA_C) * d2 * acc[nl * NC + c8 + 4 + j];
        s8 += v[j] + v[j + 4];
    }
    s8 += __shfl_xor(s8, 1);
    float inv = 1.f / s8;
#pragma unroll
    for (int j = 0; j < 8; ++j) v[j] *= inv;
    if (LAST) {
        float4 o0 = make_float4(v[0], v[1], v[2], v[3]);
        float4 o1 = make_float4(v[4], v[5], v[6], v[7]);
        *reinterpret_cast<float4*>(hout32 + (size_t)g * NC + c8) = o0;
        *reinterpret_cast<float4*>(hout32 + (size_t)g * NC + c8 + 4) = o1;
    } else {
        half4 o0, o1;
        o0.x = (_Float16)v[0]; o0.y = (_Float16)v[1];
        o0.z = (_Float16)v[2]; o0.w = (_Float16)v[3];
        o1.x = (_Float16)v[4]; o1.y = (_Float16)v[5];
        o1.z = (_Float16)v[6]; o1.w = (_Float16)v[7];
        *reinterpret_cast<half4*>(hout16 + (size_t)g * NC + c8) = o0;
        *reinterpret_cast<half4*>(hout16 + (size_t)g * NC + c8 + 4) = o1;
    }
}

// ============ fallback (atomic-cursor CSR, fp32 gather) ============

__global__ void hist_kernel(const int* __restrict__ dst, int* __restrict__ counts) {
    int e = blockIdx.x * blockDim.x + threadIdx.x;
    if (e < NE) atomicAdd(&counts[dst[e]], 1);
}

__global__ void scatter_sort(const int* __restrict__ src, const int* __restrict__ dst,
                             const float* __restrict__ ew, const float* __restrict__ W,
                             const int* __restrict__ offsets, int* __restrict__ cursor,
                             int2* __restrict__ sorted) {
    int e = blockIdx.x * blockDim.x + threadIdx.x;
    if (e >= NE) return;
    int d = dst[e];
    int s = src[e];
    int pos = offsets[d] + atomicAdd(&cursor[d], 1);
    float w = ew[e] * W[s];
    sorted[pos] = make_int2(s, __float_as_int(w));
}

__global__ void gather1(const float* __restrict__ h, const int2* __restrict__ recs,
                        const int* __restrict__ offsets, const float* __restrict__ degree,
                        float* __restrict__ hout) {
    int t = blockIdx.x * blockDim.x + threadIdx.x;
    int g = t >> 2;
    int q = t & 3;
    if (g >= NN) return;
    int q4 = q * 4;
    int beg = offsets[g];
    int end = offsets[g + 1];
    float4 acc = make_float4(0.f, 0.f, 0.f, 0.f);
    for (int i = beg; i < end; ++i) {
        int2 r0 = recs[i];
        float w0 = __int_as_float(r0.y);
        const float4 h0 = *reinterpret_cast<const float4*>(h + (size_t)(r0.x & 0x1FFFF) * NC + q4);
        acc.x += h0.x * w0; acc.y += h0.y * w0; acc.z += h0.z * w0; acc.w += h0.w * w0;
    }
    float deg = degree[g];
    float d2 = deg * deg;
    const float4 hs = *reinterpret_cast<const float4*>(h + (size_t)g * NC + q4);
    float4 v;
    v.x = ALPHA_C * hs.x + (1.f - ALPHA_C) * d2 * acc.x;
    v.y = ALPHA_C * hs.y + (1.f - ALPHA_C) * d2 * acc.y;
    v.z = ALPHA_C * hs.z + (1.f - ALPHA_C) * d2 * acc.z;
    v.w = ALPHA_C * hs.w + (1.f - ALPHA_C) * d2 * acc.w;
    float s4 = v.x + v.y + v.z + v.w;
    s4 += __shfl_xor(s4, 1);
    s4 += __shfl_xor(s4, 2);
    float inv = 1.f / s4;
    v.x *= inv; v.y *= inv; v.z *= inv; v.w *= inv;
    *reinterpret_cast<float4*>(hout + (size_t)g * NC + q4) = v;
}

// ============ launch ============

extern "C" void kernel_launch(void* const* d_in, const int* in_sizes, int n_in,
                              void* d_out, int out_size, void* d_ws, size_t ws_size,
                              hipStream_t stream)
{
    const float* x      = (const float*)d_in[0];
    const float* W      = (const float*)d_in[1];
    const float* ew     = (const float*)d_in[2];
    const float* degree = (const float*)d_in[3];
    const int*   eidx   = (const int*)d_in[4];
    const int* src = eidx;
    const int* dst = eidx + NE;
    float* out = (float*)d_out;

    const int node_blocks4 = (NN * 4 + 255) / 256;
    const int edge_blocks  = (NE + 255) / 256;

    const size_t recs_elems   = (size_t)NE;            // int2
    const size_t h16_elems    = (size_t)NN * NC;       // _Float16, x2 buffers
    const size_t counts_elems = (size_t)NBUK * NBLK + 1;
    const size_t need = recs_elems * 8 + h16_elems * 2 * 2 + counts_elems * 4
                      + 1024 * 4 + 64;

    if (ws_size >= need) {
        int2*      recs      = (int2*)d_ws;
        _Float16*  h16a      = (_Float16*)(recs + recs_elems);
        _Float16*  h16b      = h16a + h16_elems;
        int*       counts    = (int*)(h16b + h16_elems);
        int*       blockSums = counts + counts_elems;

        bucket_count<<<NBLK, 1024, 0, stream>>>(dst, counts);
        const int n_scan = NBUK * NBLK;                 // 200192
        const int NB = (n_scan + 1023) / 1024;          // 196
        scanA<<<NB, 256, 0, stream>>>(counts, blockSums, n_scan);
        scanB<<<1, 1024, 0, stream>>>(blockSums, NB);
        scanC<<<(n_scan + 255) / 256, 256, 0, stream>>>(counts, blockSums, n_scan);
        bucket_scatter<<<NBLK, 1024, 0, stream>>>(src, dst, ew, W, counts, recs);

        f32_to_f16<<<(NN * NC / 4 + 255) / 256, 256, 0, stream>>>(x, h16a);
        gather_lds<false><<<NBUK, 256, 0, stream>>>(h16a, recs, counts, degree, h16b, nullptr);
        gather_lds<false><<<NBUK, 256, 0, stream>>>(h16b, recs, counts, degree, h16a, nullptr);
        gather_lds<false><<<NBUK, 256, 0, stream>>>(h16a, recs, counts, degree, h16b, nullptr);
        gather_lds<true ><<<NBUK, 256, 0, stream>>>(h16b, recs, counts, degree, nullptr, out);
        return;
    }

    // -------- fallback: single CSR with cursor atomics, fp32 gather --------
    {
        const size_t bufA_elems = (size_t)NN * NC;
        int2*  sorted    = (int2*)d_ws;
        float* bufA      = (float*)(sorted + NE);
        int*   offsets   = (int*)(bufA + bufA_elems);
        int*   cursor    = offsets + (NN + 1);
        int*   blockSums = cursor + NN;

        (void)hipMemsetAsync(offsets, 0, (size_t)(2 * NN + 1) * sizeof(int), stream);
        hist_kernel<<<edge_blocks, 256, 0, stream>>>(dst, offsets);
        const int NB = (NN + 1023) / 1024;
        scanA<<<NB, 256, 0, stream>>>(offsets, blockSums, NN);
        scanB<<<1, 1024, 0, stream>>>(blockSums, NB);
        scanC<<<(NN + 255) / 256, 256, 0, stream>>>(offsets, blockSums, NN);
        scatter_sort<<<edge_blocks, 256, 0, stream>>>(src, dst, ew, W, offsets, cursor, sorted);

        const float* hin = x;
        float* houts[NLAYERS] = {bufA, out, bufA, out};
        for (int l = 0; l < NLAYERS; ++l) {
            gather1<<<node_blocks4, 256, 0, stream>>>(hin, sorted, offsets, degree, houts[l]);
            hin = houts[l];
        }
    }
}

// Round 11
// 214.663 us; speedup vs baseline: 6.5559x; 6.5559x over previous
//
#include <hip/hip_runtime.h>

#define NN 100000
#define NC 16
#define NE 3200000
#define NLAYERS 4
#define ALPHA_C 0.5f

#define BSHIFT 8
#define NBUK 391            // ceil(NN / 256)
#define EPB 12544           // edges per block -> exactly 256 blocks
#define NBLK 256
#define CAP 9728            // LDS staging capacity per bucket (mean 8192, +17 sigma)

typedef __attribute__((ext_vector_type(4))) _Float16 half4;
typedef __attribute__((ext_vector_type(8))) _Float16 half8;

// ============ build phase (LDS atomics only) ============

__global__ __launch_bounds__(1024) void bucket_count(const int* __restrict__ dst,
                                                     int* __restrict__ counts) {
    __shared__ int h[NBUK];
    for (int i = threadIdx.x; i < NBUK; i += 1024) h[i] = 0;
    __syncthreads();
    int base = blockIdx.x * EPB;
    int nedge = min(EPB, NE - base);
    for (int i = threadIdx.x; i < nedge; i += 1024)
        atomicAdd(&h[dst[base + i] >> BSHIFT], 1);
    __syncthreads();
    for (int i = threadIdx.x; i < NBUK; i += 1024)
        counts[i * NBLK + blockIdx.x] = h[i];   // bucket-major for the scan
}

// Exclusive scan, 1024 elements per block (256 threads x 4 elems).
__global__ void scanA(int* __restrict__ data, int* __restrict__ blockSums, int n) {
    __shared__ int lds[256];
    int base = blockIdx.x * 1024 + threadIdx.x * 4;
    int v[4] = {0, 0, 0, 0};
#pragma unroll
    for (int i = 0; i < 4; ++i) { int idx = base + i; if (idx < n) v[i] = data[idx]; }
    int tsum = v[0] + v[1] + v[2] + v[3];
    lds[threadIdx.x] = tsum;
    __syncthreads();
    for (int off = 1; off < 256; off <<= 1) {
        int t = (threadIdx.x >= off) ? lds[threadIdx.x - off] : 0;
        __syncthreads();
        lds[threadIdx.x] += t;
        __syncthreads();
    }
    if (threadIdx.x == 255) blockSums[blockIdx.x] = lds[255];
    int run = lds[threadIdx.x] - tsum;
#pragma unroll
    for (int i = 0; i < 4; ++i) {
        int idx = base + i;
        if (idx < n) { int old = v[i]; data[idx] = run; run += old; }
    }
}

__global__ void scanB(int* __restrict__ blockSums, int nb) {
    __shared__ int lds[1024];
    int t = threadIdx.x;
    lds[t] = (t < nb) ? blockSums[t] : 0;
    __syncthreads();
    for (int off = 1; off < 1024; off <<= 1) {
        int v = (t >= off) ? lds[t - off] : 0;
        __syncthreads();
        lds[t] += v;
        __syncthreads();
    }
    if (t < nb) blockSums[t] = (t == 0) ? 0 : lds[t - 1];
}

__global__ void scanC(int* __restrict__ data, const int* __restrict__ blockSums, int n) {
    int idx = blockIdx.x * blockDim.x + threadIdx.x;
    if (idx < n) data[idx] += blockSums[idx >> 10];
    if (idx == 0) data[n] = NE;
}

// LDS-staged scatter: histogram -> LDS scan -> LDS placement (bucket-ordered)
// -> linear coalesced write-out. rec.x = src | (local_dst<<17), rec.y = w bits.
__global__ __launch_bounds__(1024) void bucket_scatter(
        const int* __restrict__ src, const int* __restrict__ dst,
        const float* __restrict__ ew, const float* __restrict__ W,
        const int* __restrict__ scanned, int2* __restrict__ recs) {
    __shared__ int2 lrec[EPB];               // 100352 B
    __shared__ unsigned short lbid[EPB];     // 25088 B
    __shared__ int h[NBUK];
    __shared__ int lbase[NBUK];
    __shared__ int delta[NBUK];
    __shared__ int sc[512];
    int t = threadIdx.x;
    int blk = blockIdx.x;
    for (int i = t; i < NBUK; i += 1024) h[i] = 0;
    __syncthreads();
    int base = blk * EPB;
    int nedge = min(EPB, NE - base);
    for (int i = t; i < nedge; i += 1024)
        atomicAdd(&h[dst[base + i] >> BSHIFT], 1);
    __syncthreads();
    // exclusive LDS scan of h -> lbase; delta = global base - local base
    if (t < 512) sc[t] = (t < NBUK) ? h[t] : 0;
    __syncthreads();
    for (int off = 1; off < 512; off <<= 1) {
        int v = (t >= off && t < 512) ? sc[t - off] : 0;
        __syncthreads();
        if (t < 512) sc[t] += v;
        __syncthreads();
    }
    if (t < NBUK) {
        int excl = sc[t] - h[t];
        lbase[t] = excl;
        delta[t] = scanned[t * NBLK + blk] - excl;
        h[t] = 0;
    }
    __syncthreads();
    // placement into LDS, bucket-ordered
    for (int i = t; i < nedge; i += 1024) {
        int e = base + i;
        int d = dst[e];
        int s = src[e];
        float w = ew[e] * W[s];
        int b = d >> BSHIFT;
        int r = atomicAdd(&h[b], 1);
        int slot = lbase[b] + r;
        lrec[slot] = make_int2(s | ((d & 255) << 17), __float_as_int(w));
        lbid[slot] = (unsigned short)b;
    }
    __syncthreads();
    // coalesced write-out: consecutive threads -> consecutive addresses per run
    for (int i = t; i < nedge; i += 1024) {
        int b = lbid[i];
        recs[i + delta[b]] = lrec[i];
    }
}

// One block (512 thr) per bucket: stage records in LDS, counting-sort the 256
// local dsts, write CSR offsets, rewrite records in place fully dst-sorted.
__global__ void bucket_sort(int2* __restrict__ recs, const int* __restrict__ scanned,
                            int* __restrict__ offsets) {
    __shared__ int2 lrec[CAP];
    __shared__ int hcnt[256];
    __shared__ int hscan[256];
    __shared__ int hexcl[256];
    int b = blockIdx.x;
    int t = threadIdx.x;
    int beg = scanned[b * NBLK];
    int end = (b == NBUK - 1) ? NE : scanned[(b + 1) * NBLK];
    int cnt = end - beg;
    if (t < 256) hcnt[t] = 0;
    __syncthreads();
    for (int i = t; i < cnt && i < CAP; i += 512) {
        int2 rv = recs[beg + i];
        lrec[i] = rv;
        atomicAdd(&hcnt[(rv.x >> 17) & 255], 1);
    }
    __syncthreads();
    if (t < 256) hscan[t] = hcnt[t];
    __syncthreads();
    for (int off = 1; off < 256; off <<= 1) {
        int v = 0;
        if (t >= off && t < 256) v = hscan[t - off];
        __syncthreads();
        if (t < 256) hscan[t] += v;
        __syncthreads();
    }
    if (t < 256) {
        hexcl[t] = hscan[t] - hcnt[t];
        int d = (b << BSHIFT) + t;
        if (d < NN) offsets[d] = beg + hexcl[t];
        hcnt[t] = 0;
    }
    if (b == NBUK - 1 && t == 0) offsets[NN] = NE;
    __syncthreads();
    for (int i = t; i < cnt && i < CAP; i += 512) {
        int2 rv = lrec[i];
        int ld = (rv.x >> 17) & 255;
        int r = atomicAdd(&hcnt[ld], 1);
        recs[beg + hexcl[ld] + r] = make_int2(rv.x & 0x1FFFF, rv.y);
    }
}

// ============ fp32 -> fp16 conversion (once) ============
__global__ void f32_to_f16(const float* __restrict__ in, _Float16* __restrict__ out) {
    int i = blockIdx.x * blockDim.x + threadIdx.x;
    int base = i * 4;
    if (base < NN * NC) {
        float4 v = *reinterpret_cast<const float4*>(in + base);
        half4 o;
        o.x = (_Float16)v.x; o.y = (_Float16)v.y;
        o.z = (_Float16)v.z; o.w = (_Float16)v.w;
        *reinterpret_cast<half4*>(out + base) = o;
    }
}

// ============ per-layer gather (fp16 h, 8 lanes/node: 2 class-halves x 4 edge-quarters) ============
// sub = t&7: q = sub&1 owns classes [8q,8q+8) (one 16B half8 load per edge);
// quarter = sub>>1 owns an edge quarter (chain ~8, 4-wide unroll).
// Quarters merged via shfl_xor(2)+shfl_xor(4); rownorm via shfl_xor(1).
template<bool LAST>
__global__ __launch_bounds__(256) void gather_f16(
        const _Float16* __restrict__ h, const int2* __restrict__ recs,
        const int* __restrict__ offsets, const float* __restrict__ degree,
        _Float16* __restrict__ hout16, float* __restrict__ hout32) {
    int t = blockIdx.x * blockDim.x + threadIdx.x;
    int g = t >> 3;
    int sub = t & 7;
    int q = sub & 1;
    int quarter = sub >> 1;
    if (g >= NN) return;
    int q8 = q * 8;
    int beg = offsets[g];
    int end = offsets[g + 1];
    int len = end - beg;
    int qlen = (len + 3) >> 2;
    int lo = beg + quarter * qlen;
    int hi = lo + qlen;
    if (lo > end) lo = end;
    if (hi > end) hi = end;
    float acc[8] = {0.f, 0.f, 0.f, 0.f, 0.f, 0.f, 0.f, 0.f};
    int i = lo;
    for (; i + 4 <= hi; i += 4) {
        long long v0 = __builtin_nontemporal_load((const long long*)(recs + i));
        long long v1 = __builtin_nontemporal_load((const long long*)(recs + i + 1));
        long long v2 = __builtin_nontemporal_load((const long long*)(recs + i + 2));
        long long v3 = __builtin_nontemporal_load((const long long*)(recs + i + 3));
        int s0 = (int)v0, s1 = (int)v1, s2 = (int)v2, s3 = (int)v3;
        const half8 h0 = *reinterpret_cast<const half8*>(h + (size_t)s0 * NC + q8);
        const half8 h1 = *reinterpret_cast<const half8*>(h + (size_t)s1 * NC + q8);
        const half8 h2 = *reinterpret_cast<const half8*>(h + (size_t)s2 * NC + q8);
        const half8 h3 = *reinterpret_cast<const half8*>(h + (size_t)s3 * NC + q8);
        float w0 = __int_as_float((int)(v0 >> 32)), w1 = __int_as_float((int)(v1 >> 32));
        float w2 = __int_as_float((int)(v2 >> 32)), w3 = __int_as_float((int)(v3 >> 32));
#pragma unroll
        for (int j = 0; j < 8; ++j) {
            acc[j] += (float)h0[j] * w0 + (float)h1[j] * w1
                    + (float)h2[j] * w2 + (float)h3[j] * w3;
        }
    }
    for (; i < hi; ++i) {
        long long v0 = __builtin_nontemporal_load((const long long*)(recs + i));
        int s0 = (int)v0;
        float w0 = __int_as_float((int)(v0 >> 32));
        const half8 h0 = *reinterpret_cast<const half8*>(h + (size_t)s0 * NC + q8);
#pragma unroll
        for (int j = 0; j < 8; ++j) acc[j] += (float)h0[j] * w0;
    }
    // merge the 4 edge-quarters (lanes differ in bits 1-2 of sub)
#pragma unroll
    for (int j = 0; j < 8; ++j) {
        acc[j] += __shfl_xor(acc[j], 2);
        acc[j] += __shfl_xor(acc[j], 4);
    }
    float deg = degree[g];
    float d2 = deg * deg;
    const half8 hsv = *reinterpret_cast<const half8*>(h + (size_t)g * NC + q8);
    float v[8];
    float s8 = 0.f;
#pragma unroll
    for (int j = 0; j < 8; ++j) {
        v[j] = ALPHA_C * (float)hsv[j] + (1.f - ALPHA_C) * d2 * acc[j];
        s8 += v[j];
    }
    s8 += __shfl_xor(s8, 1);   // add the other class-half
    float inv = 1.f / s8;
#pragma unroll
    for (int j = 0; j < 8; ++j) v[j] *= inv;
    if (quarter == 0) {
        if (LAST) {
            float4 o0 = make_float4(v[0], v[1], v[2], v[3]);
            float4 o1 = make_float4(v[4], v[5], v[6], v[7]);
            *reinterpret_cast<float4*>(hout32 + (size_t)g * NC + q8) = o0;
            *reinterpret_cast<float4*>(hout32 + (size_t)g * NC + q8 + 4) = o1;
        } else {
            half8 o;
#pragma unroll
            for (int j = 0; j < 8; ++j) o[j] = (_Float16)v[j];
            *reinterpret_cast<half8*>(hout16 + (size_t)g * NC + q8) = o;
        }
    }
}

// ============ fallback (atomic-cursor CSR, fp32 gather) ============

__global__ void hist_kernel(const int* __restrict__ dst, int* __restrict__ counts) {
    int e = blockIdx.x * blockDim.x + threadIdx.x;
    if (e < NE) atomicAdd(&counts[dst[e]], 1);
}

__global__ void scatter_sort(const int* __restrict__ src, const int* __restrict__ dst,
                             const float* __restrict__ ew, const float* __restrict__ W,
                             const int* __restrict__ offsets, int* __restrict__ cursor,
                             int2* __restrict__ sorted) {
    int e = blockIdx.x * blockDim.x + threadIdx.x;
    if (e >= NE) return;
    int d = dst[e];
    int s = src[e];
    int pos = offsets[d] + atomicAdd(&cursor[d], 1);
    float w = ew[e] * W[s];
    sorted[pos] = make_int2(s, __float_as_int(w));
}

__global__ void gather1(const float* __restrict__ h, const int2* __restrict__ recs,
                        const int* __restrict__ offsets, const float* __restrict__ degree,
                        float* __restrict__ hout) {
    int t = blockIdx.x * blockDim.x + threadIdx.x;
    int g = t >> 2;
    int q = t & 3;
    if (g >= NN) return;
    int q4 = q * 4;
    int beg = offsets[g];
    int end = offsets[g + 1];
    float4 acc = make_float4(0.f, 0.f, 0.f, 0.f);
    for (int i = beg; i < end; ++i) {
        int2 r0 = recs[i];
        float w0 = __int_as_float(r0.y);
        const float4 h0 = *reinterpret_cast<const float4*>(h + (size_t)(r0.x & 0x1FFFF) * NC + q4);
        acc.x += h0.x * w0; acc.y += h0.y * w0; acc.z += h0.z * w0; acc.w += h0.w * w0;
    }
    float deg = degree[g];
    float d2 = deg * deg;
    const float4 hs = *reinterpret_cast<const float4*>(h + (size_t)g * NC + q4);
    float4 v;
    v.x = ALPHA_C * hs.x + (1.f - ALPHA_C) * d2 * acc.x;
    v.y = ALPHA_C * hs.y + (1.f - ALPHA_C) * d2 * acc.y;
    v.z = ALPHA_C * hs.z + (1.f - ALPHA_C) * d2 * acc.z;
    v.w = ALPHA_C * hs.w + (1.f - ALPHA_C) * d2 * acc.w;
    float s4 = v.x + v.y + v.z + v.w;
    s4 += __shfl_xor(s4, 1);
    s4 += __shfl_xor(s4, 2);
    float inv = 1.f / s4;
    v.x *= inv; v.y *= inv; v.z *= inv; v.w *= inv;
    *reinterpret_cast<float4*>(hout + (size_t)g * NC + q4) = v;
}

// ============ launch ============

extern "C" void kernel_launch(void* const* d_in, const int* in_sizes, int n_in,
                              void* d_out, int out_size, void* d_ws, size_t ws_size,
                              hipStream_t stream)
{
    const float* x      = (const float*)d_in[0];
    const float* W      = (const float*)d_in[1];
    const float* ew     = (const float*)d_in[2];
    const float* degree = (const float*)d_in[3];
    const int*   eidx   = (const int*)d_in[4];
    const int* src = eidx;
    const int* dst = eidx + NE;
    float* out = (float*)d_out;

    const int node_blocks8 = (NN * 8 + 255) / 256;     // 8 lanes per node
    const int node_blocks4 = (NN * 4 + 255) / 256;
    const int edge_blocks  = (NE + 255) / 256;

    const size_t recs_elems   = (size_t)NE;            // int2
    const size_t h16_elems    = (size_t)NN * NC;       // _Float16, x2 buffers
    const size_t counts_elems = (size_t)NBUK * NBLK + 1;
    const size_t off_elems    = (size_t)NN + 1;
    const size_t need = recs_elems * 8 + h16_elems * 2 * 2 + counts_elems * 4
                      + off_elems * 4 + 1024 * 4 + 64;

    if (ws_size >= need) {
        int2*      recs      = (int2*)d_ws;
        _Float16*  h16a      = (_Float16*)(recs + recs_elems);
        _Float16*  h16b      = h16a + h16_elems;
        int*       counts    = (int*)(h16b + h16_elems);
        int*       offsets   = counts + counts_elems;
        int*       blockSums = offsets + off_elems;

        bucket_count<<<NBLK, 1024, 0, stream>>>(dst, counts);
        const int n_scan = NBUK * NBLK;                 // 100096
        const int NB = (n_scan + 1023) / 1024;          // 98
        scanA<<<NB, 256, 0, stream>>>(counts, blockSums, n_scan);
        scanB<<<1, 1024, 0, stream>>>(blockSums, NB);
        scanC<<<(n_scan + 255) / 256, 256, 0, stream>>>(counts, blockSums, n_scan);
        bucket_scatter<<<NBLK, 1024, 0, stream>>>(src, dst, ew, W, counts, recs);
        bucket_sort<<<NBUK, 512, 0, stream>>>(recs, counts, offsets);

        f32_to_f16<<<(NN * NC / 4 + 255) / 256, 256, 0, stream>>>(x, h16a);
        gather_f16<false><<<node_blocks8, 256, 0, stream>>>(h16a, recs, offsets, degree, h16b, nullptr);
        gather_f16<false><<<node_blocks8, 256, 0, stream>>>(h16b, recs, offsets, degree, h16a, nullptr);
        gather_f16<false><<<node_blocks8, 256, 0, stream>>>(h16a, recs, offsets, degree, h16b, nullptr);
        gather_f16<true ><<<node_blocks8, 256, 0, stream>>>(h16b, recs, offsets, degree, nullptr, out);
        return;
    }

    // -------- fallback: single CSR with cursor atomics, fp32 gather --------
    {
        const size_t bufA_elems = (size_t)NN * NC;
        int2*  sorted    = (int2*)d_ws;
        float* bufA      = (float*)(sorted + NE);
        int*   offsets   = (int*)(bufA + bufA_elems);
        int*   cursor    = offsets + (NN + 1);
        int*   blockSums = cursor + NN;

        (void)hipMemsetAsync(offsets, 0, (size_t)(2 * NN + 1) * sizeof(int), stream);
        hist_kernel<<<edge_blocks, 256, 0, stream>>>(dst, offsets);
        const int NB = (NN + 1023) / 1024;
        scanA<<<NB, 256, 0, stream>>>(offsets, blockSums, NN);
        scanB<<<1, 1024, 0, stream>>>(blockSums, NB);
        scanC<<<(NN + 255) / 256, 256, 0, stream>>>(offsets, blockSums, NN);
        scatter_sort<<<edge_blocks, 256, 0, stream>>>(src, dst, ew, W, offsets, cursor, sorted);

        const float* hin = x;
        float* houts[NLAYERS] = {bufA, out, bufA, out};
        for (int l = 0; l < NLAYERS; ++l) {
            gather1<<<node_blocks4, 256, 0, stream>>>(hin, sorted, offsets, degree, houts[l]);
            hin = houts[l];
        }
    }
}

// Round 12
// 191.773 us; speedup vs baseline: 7.3384x; 1.1194x over previous
//
#include <hip/hip_runtime.h>

#define NN 100000
#define NC 16
#define NE 3200000
#define NLAYERS 4
#define ALPHA_C 0.5f

#define BSHIFT 8
#define NBUK 391            // ceil(NN / 256)
#define EPB 12544           // edges per block -> exactly 256 blocks
#define NBLK 256
#define CAP 9728            // LDS staging capacity per bucket (mean 8192, +17 sigma)

typedef __attribute__((ext_vector_type(4))) _Float16 half4;
typedef __attribute__((ext_vector_type(8))) _Float16 half8;

static __device__ __forceinline__ unsigned short f2h_bits(float w) {
    _Float16 h = (_Float16)w;
    unsigned short b;
    __builtin_memcpy(&b, &h, 2);
    return b;
}
static __device__ __forceinline__ float hbits2f(unsigned short b) {
    _Float16 h;
    __builtin_memcpy(&h, &b, 2);
    return (float)h;
}

// ============ build phase (LDS atomics only) ============

__global__ __launch_bounds__(1024) void bucket_count(const int* __restrict__ dst,
                                                     int* __restrict__ counts) {
    __shared__ int h[NBUK];
    for (int i = threadIdx.x; i < NBUK; i += 1024) h[i] = 0;
    __syncthreads();
    int base = blockIdx.x * EPB;
    int nedge = min(EPB, NE - base);
    for (int i = threadIdx.x; i < nedge; i += 1024)
        atomicAdd(&h[dst[base + i] >> BSHIFT], 1);
    __syncthreads();
    for (int i = threadIdx.x; i < NBUK; i += 1024)
        counts[i * NBLK + blockIdx.x] = h[i];   // bucket-major for the scan
}

// Exclusive scan, 1024 elements per block (256 threads x 4 elems).
__global__ void scanA(int* __restrict__ data, int* __restrict__ blockSums, int n) {
    __shared__ int lds[256];
    int base = blockIdx.x * 1024 + threadIdx.x * 4;
    int v[4] = {0, 0, 0, 0};
#pragma unroll
    for (int i = 0; i < 4; ++i) { int idx = base + i; if (idx < n) v[i] = data[idx]; }
    int tsum = v[0] + v[1] + v[2] + v[3];
    lds[threadIdx.x] = tsum;
    __syncthreads();
    for (int off = 1; off < 256; off <<= 1) {
        int t = (threadIdx.x >= off) ? lds[threadIdx.x - off] : 0;
        __syncthreads();
        lds[threadIdx.x] += t;
        __syncthreads();
    }
    if (threadIdx.x == 255) blockSums[blockIdx.x] = lds[255];
    int run = lds[threadIdx.x] - tsum;
#pragma unroll
    for (int i = 0; i < 4; ++i) {
        int idx = base + i;
        if (idx < n) { int old = v[i]; data[idx] = run; run += old; }
    }
}

__global__ void scanB(int* __restrict__ blockSums, int nb) {
    __shared__ int lds[1024];
    int t = threadIdx.x;
    lds[t] = (t < nb) ? blockSums[t] : 0;
    __syncthreads();
    for (int off = 1; off < 1024; off <<= 1) {
        int v = (t >= off) ? lds[t - off] : 0;
        __syncthreads();
        lds[t] += v;
        __syncthreads();
    }
    if (t < nb) blockSums[t] = (t == 0) ? 0 : lds[t - 1];
}

__global__ void scanC(int* __restrict__ data, const int* __restrict__ blockSums, int n) {
    int idx = blockIdx.x * blockDim.x + threadIdx.x;
    if (idx < n) data[idx] += blockSums[idx >> 10];
    if (idx == 0) data[n] = NE;
}

// LDS-staged scatter: histogram -> LDS scan -> LDS placement (bucket-ordered)
// -> linear coalesced write-out. rec.x = src | (local_dst<<17), rec.y = w bits.
__global__ __launch_bounds__(1024) void bucket_scatter(
        const int* __restrict__ src, const int* __restrict__ dst,
        const float* __restrict__ ew, const float* __restrict__ W,
        const int* __restrict__ scanned, int2* __restrict__ recs) {
    __shared__ int2 lrec[EPB];               // 100352 B
    __shared__ unsigned short lbid[EPB];     // 25088 B
    __shared__ int h[NBUK];
    __shared__ int lbase[NBUK];
    __shared__ int delta[NBUK];
    __shared__ int sc[512];
    int t = threadIdx.x;
    int blk = blockIdx.x;
    for (int i = t; i < NBUK; i += 1024) h[i] = 0;
    __syncthreads();
    int base = blk * EPB;
    int nedge = min(EPB, NE - base);
    for (int i = t; i < nedge; i += 1024)
        atomicAdd(&h[dst[base + i] >> BSHIFT], 1);
    __syncthreads();
    // exclusive LDS scan of h -> lbase; delta = global base - local base
    if (t < 512) sc[t] = (t < NBUK) ? h[t] : 0;
    __syncthreads();
    for (int off = 1; off < 512; off <<= 1) {
        int v = (t >= off && t < 512) ? sc[t - off] : 0;
        __syncthreads();
        if (t < 512) sc[t] += v;
        __syncthreads();
    }
    if (t < NBUK) {
        int excl = sc[t] - h[t];
        lbase[t] = excl;
        delta[t] = scanned[t * NBLK + blk] - excl;
        h[t] = 0;
    }
    __syncthreads();
    // placement into LDS, bucket-ordered
    for (int i = t; i < nedge; i += 1024) {
        int e = base + i;
        int d = dst[e];
        int s = src[e];
        float w = ew[e] * W[s];
        int b = d >> BSHIFT;
        int r = atomicAdd(&h[b], 1);
        int slot = lbase[b] + r;
        lrec[slot] = make_int2(s | ((d & 255) << 17), __float_as_int(w));
        lbid[slot] = (unsigned short)b;
    }
    __syncthreads();
    // coalesced write-out: consecutive threads -> consecutive addresses per run
    for (int i = t; i < nedge; i += 1024) {
        int b = lbid[i];
        recs[i + delta[b]] = lrec[i];
    }
}

// One block (512 thr) per bucket: stage 8B records in LDS, counting-sort the
// 256 local dsts, write CSR offsets, and emit PACKED 4B records
// (src 17b | fp16-w-no-sign 15b), fully dst-sorted.
__global__ void bucket_sort(const int2* __restrict__ recs, unsigned* __restrict__ recs4,
                            const int* __restrict__ scanned, int* __restrict__ offsets) {
    __shared__ int2 lrec[CAP];
    __shared__ int hcnt[256];
    __shared__ int hscan[256];
    __shared__ int hexcl[256];
    int b = blockIdx.x;
    int t = threadIdx.x;
    int beg = scanned[b * NBLK];
    int end = (b == NBUK - 1) ? NE : scanned[(b + 1) * NBLK];
    int cnt = end - beg;
    if (t < 256) hcnt[t] = 0;
    __syncthreads();
    for (int i = t; i < cnt && i < CAP; i += 512) {
        int2 rv = recs[beg + i];
        lrec[i] = rv;
        atomicAdd(&hcnt[(rv.x >> 17) & 255], 1);
    }
    __syncthreads();
    if (t < 256) hscan[t] = hcnt[t];
    __syncthreads();
    for (int off = 1; off < 256; off <<= 1) {
        int v = 0;
        if (t >= off && t < 256) v = hscan[t - off];
        __syncthreads();
        if (t < 256) hscan[t] += v;
        __syncthreads();
    }
    if (t < 256) {
        hexcl[t] = hscan[t] - hcnt[t];
        int d = (b << BSHIFT) + t;
        if (d < NN) offsets[d] = beg + hexcl[t];
        hcnt[t] = 0;
    }
    if (b == NBUK - 1 && t == 0) offsets[NN] = NE;
    __syncthreads();
    for (int i = t; i < cnt && i < CAP; i += 512) {
        int2 rv = lrec[i];
        int ld = (rv.x >> 17) & 255;
        int r = atomicAdd(&hcnt[ld], 1);
        unsigned short hb = f2h_bits(__int_as_float(rv.y));
        recs4[beg + hexcl[ld] + r] = (unsigned)(rv.x & 0x1FFFF) | ((unsigned)hb << 17);
    }
}

// ============ fp32 -> fp16 conversion (once) ============
__global__ void f32_to_f16(const float* __restrict__ in, _Float16* __restrict__ out) {
    int i = blockIdx.x * blockDim.x + threadIdx.x;
    int base = i * 4;
    if (base < NN * NC) {
        float4 v = *reinterpret_cast<const float4*>(in + base);
        half4 o;
        o.x = (_Float16)v.x; o.y = (_Float16)v.y;
        o.z = (_Float16)v.z; o.w = (_Float16)v.w;
        *reinterpret_cast<half4*>(out + base) = o;
    }
}

// ============ per-layer gather (fp16 h, packed 4B recs, 8 lanes/node) ============
// sub = t&7: q = sub&1 owns classes [8q,8q+8) (one 16B half8 load per edge);
// quarter = sub>>1 owns an edge quarter. Quarters merged via shfl_xor(2,4);
// rownorm via shfl_xor(1).
template<bool LAST>
__global__ __launch_bounds__(256) void gather_f16(
        const _Float16* __restrict__ h, const unsigned* __restrict__ recs,
        const int* __restrict__ offsets, const float* __restrict__ degree,
        _Float16* __restrict__ hout16, float* __restrict__ hout32) {
    int t = blockIdx.x * blockDim.x + threadIdx.x;
    int g = t >> 3;
    int sub = t & 7;
    int q = sub & 1;
    int quarter = sub >> 1;
    if (g >= NN) return;
    int q8 = q * 8;
    int beg = offsets[g];
    int end = offsets[g + 1];
    int len = end - beg;
    int qlen = (len + 3) >> 2;
    int lo = beg + quarter * qlen;
    int hi = lo + qlen;
    if (lo > end) lo = end;
    if (hi > end) hi = end;
    float acc[8] = {0.f, 0.f, 0.f, 0.f, 0.f, 0.f, 0.f, 0.f};
    int i = lo;
    for (; i + 4 <= hi; i += 4) {
        unsigned r0 = __builtin_nontemporal_load(recs + i);
        unsigned r1 = __builtin_nontemporal_load(recs + i + 1);
        unsigned r2 = __builtin_nontemporal_load(recs + i + 2);
        unsigned r3 = __builtin_nontemporal_load(recs + i + 3);
        int s0 = r0 & 0x1FFFF, s1 = r1 & 0x1FFFF, s2 = r2 & 0x1FFFF, s3 = r3 & 0x1FFFF;
        const half8 h0 = *reinterpret_cast<const half8*>(h + (size_t)s0 * NC + q8);
        const half8 h1 = *reinterpret_cast<const half8*>(h + (size_t)s1 * NC + q8);
        const half8 h2 = *reinterpret_cast<const half8*>(h + (size_t)s2 * NC + q8);
        const half8 h3 = *reinterpret_cast<const half8*>(h + (size_t)s3 * NC + q8);
        float w0 = hbits2f((unsigned short)(r0 >> 17));
        float w1 = hbits2f((unsigned short)(r1 >> 17));
        float w2 = hbits2f((unsigned short)(r2 >> 17));
        float w3 = hbits2f((unsigned short)(r3 >> 17));
#pragma unroll
        for (int j = 0; j < 8; ++j) {
            acc[j] += (float)h0[j] * w0 + (float)h1[j] * w1
                    + (float)h2[j] * w2 + (float)h3[j] * w3;
        }
    }
    for (; i < hi; ++i) {
        unsigned r0 = __builtin_nontemporal_load(recs + i);
        int s0 = r0 & 0x1FFFF;
        float w0 = hbits2f((unsigned short)(r0 >> 17));
        const half8 h0 = *reinterpret_cast<const half8*>(h + (size_t)s0 * NC + q8);
#pragma unroll
        for (int j = 0; j < 8; ++j) acc[j] += (float)h0[j] * w0;
    }
    // merge the 4 edge-quarters (lanes differ in bits 1-2 of sub)
#pragma unroll
    for (int j = 0; j < 8; ++j) {
        acc[j] += __shfl_xor(acc[j], 2);
        acc[j] += __shfl_xor(acc[j], 4);
    }
    float deg = degree[g];
    float d2 = deg * deg;
    const half8 hsv = *reinterpret_cast<const half8*>(h + (size_t)g * NC + q8);
    float v[8];
    float s8 = 0.f;
#pragma unroll
    for (int j = 0; j < 8; ++j) {
        v[j] = ALPHA_C * (float)hsv[j] + (1.f - ALPHA_C) * d2 * acc[j];
        s8 += v[j];
    }
    s8 += __shfl_xor(s8, 1);   // add the other class-half
    float inv = 1.f / s8;
#pragma unroll
    for (int j = 0; j < 8; ++j) v[j] *= inv;
    if (quarter == 0) {
        if (LAST) {
            float4 o0 = make_float4(v[0], v[1], v[2], v[3]);
            float4 o1 = make_float4(v[4], v[5], v[6], v[7]);
            *reinterpret_cast<float4*>(hout32 + (size_t)g * NC + q8) = o0;
            *reinterpret_cast<float4*>(hout32 + (size_t)g * NC + q8 + 4) = o1;
        } else {
            half8 o;
#pragma unroll
            for (int j = 0; j < 8; ++j) o[j] = (_Float16)v[j];
            *reinterpret_cast<half8*>(hout16 + (size_t)g * NC + q8) = o;
        }
    }
}

// ============ fallback (atomic-cursor CSR, fp32 gather) ============

__global__ void hist_kernel(const int* __restrict__ dst, int* __restrict__ counts) {
    int e = blockIdx.x * blockDim.x + threadIdx.x;
    if (e < NE) atomicAdd(&counts[dst[e]], 1);
}

__global__ void scatter_sort(const int* __restrict__ src, const int* __restrict__ dst,
                             const float* __restrict__ ew, const float* __restrict__ W,
                             const int* __restrict__ offsets, int* __restrict__ cursor,
                             int2* __restrict__ sorted) {
    int e = blockIdx.x * blockDim.x + threadIdx.x;
    if (e >= NE) return;
    int d = dst[e];
    int s = src[e];
    int pos = offsets[d] + atomicAdd(&cursor[d], 1);
    float w = ew[e] * W[s];
    sorted[pos] = make_int2(s, __float_as_int(w));
}

__global__ void gather1(const float* __restrict__ h, const int2* __restrict__ recs,
                        const int* __restrict__ offsets, const float* __restrict__ degree,
                        float* __restrict__ hout) {
    int t = blockIdx.x * blockDim.x + threadIdx.x;
    int g = t >> 2;
    int q = t & 3;
    if (g >= NN) return;
    int q4 = q * 4;
    int beg = offsets[g];
    int end = offsets[g + 1];
    float4 acc = make_float4(0.f, 0.f, 0.f, 0.f);
    for (int i = beg; i < end; ++i) {
        int2 r0 = recs[i];
        float w0 = __int_as_float(r0.y);
        const float4 h0 = *reinterpret_cast<const float4*>(h + (size_t)(r0.x & 0x1FFFF) * NC + q4);
        acc.x += h0.x * w0; acc.y += h0.y * w0; acc.z += h0.z * w0; acc.w += h0.w * w0;
    }
    float deg = degree[g];
    float d2 = deg * deg;
    const float4 hs = *reinterpret_cast<const float4*>(h + (size_t)g * NC + q4);
    float4 v;
    v.x = ALPHA_C * hs.x + (1.f - ALPHA_C) * d2 * acc.x;
    v.y = ALPHA_C * hs.y + (1.f - ALPHA_C) * d2 * acc.y;
    v.z = ALPHA_C * hs.z + (1.f - ALPHA_C) * d2 * acc.z;
    v.w = ALPHA_C * hs.w + (1.f - ALPHA_C) * d2 * acc.w;
    float s4 = v.x + v.y + v.z + v.w;
    s4 += __shfl_xor(s4, 1);
    s4 += __shfl_xor(s4, 2);
    float inv = 1.f / s4;
    v.x *= inv; v.y *= inv; v.z *= inv; v.w *= inv;
    *reinterpret_cast<float4*>(hout + (size_t)g * NC + q4) = v;
}

// ============ launch ============

extern "C" void kernel_launch(void* const* d_in, const int* in_sizes, int n_in,
                              void* d_out, int out_size, void* d_ws, size_t ws_size,
                              hipStream_t stream)
{
    const float* x      = (const float*)d_in[0];
    const float* W      = (const float*)d_in[1];
    const float* ew     = (const float*)d_in[2];
    const float* degree = (const float*)d_in[3];
    const int*   eidx   = (const int*)d_in[4];
    const int* src = eidx;
    const int* dst = eidx + NE;
    float* out = (float*)d_out;

    const int node_blocks8 = (NN * 8 + 255) / 256;     // 8 lanes per node
    const int node_blocks4 = (NN * 4 + 255) / 256;
    const int edge_blocks  = (NE + 255) / 256;

    const size_t recs_elems   = (size_t)NE;            // int2 (build)
    const size_t recs4_elems  = (size_t)NE;            // u32 (gather)
    const size_t h16_elems    = (size_t)NN * NC;       // _Float16, x2 buffers
    const size_t counts_elems = (size_t)NBUK * NBLK + 1;
    const size_t off_elems    = (size_t)NN + 1;
    const size_t need = recs_elems * 8 + recs4_elems * 4 + h16_elems * 2 * 2
                      + counts_elems * 4 + off_elems * 4 + 1024 * 4 + 64;

    if (ws_size >= need) {
        int2*      recs      = (int2*)d_ws;
        unsigned*  recs4     = (unsigned*)(recs + recs_elems);
        _Float16*  h16a      = (_Float16*)(recs4 + recs4_elems);
        _Float16*  h16b      = h16a + h16_elems;
        int*       counts    = (int*)(h16b + h16_elems);
        int*       offsets   = counts + counts_elems;
        int*       blockSums = offsets + off_elems;

        bucket_count<<<NBLK, 1024, 0, stream>>>(dst, counts);
        const int n_scan = NBUK * NBLK;                 // 100096
        const int NB = (n_scan + 1023) / 1024;          // 98
        scanA<<<NB, 256, 0, stream>>>(counts, blockSums, n_scan);
        scanB<<<1, 1024, 0, stream>>>(blockSums, NB);
        scanC<<<(n_scan + 255) / 256, 256, 0, stream>>>(counts, blockSums, n_scan);
        bucket_scatter<<<NBLK, 1024, 0, stream>>>(src, dst, ew, W, counts, recs);
        bucket_sort<<<NBUK, 512, 0, stream>>>(recs, recs4, counts, offsets);

        f32_to_f16<<<(NN * NC / 4 + 255) / 256, 256, 0, stream>>>(x, h16a);
        gather_f16<false><<<node_blocks8, 256, 0, stream>>>(h16a, recs4, offsets, degree, h16b, nullptr);
        gather_f16<false><<<node_blocks8, 256, 0, stream>>>(h16b, recs4, offsets, degree, h16a, nullptr);
        gather_f16<false><<<node_blocks8, 256, 0, stream>>>(h16a, recs4, offsets, degree, h16b, nullptr);
        gather_f16<true ><<<node_blocks8, 256, 0, stream>>>(h16b, recs4, offsets, degree, nullptr, out);
        return;
    }

    // -------- fallback: single CSR with cursor atomics, fp32 gather --------
    {
        const size_t bufA_elems = (size_t)NN * NC;
        int2*  sorted    = (int2*)d_ws;
        float* bufA      = (float*)(sorted + NE);
        int*   offsets   = (int*)(bufA + bufA_elems);
        int*   cursor    = offsets + (NN + 1);
        int*   blockSums = cursor + NN;

        (void)hipMemsetAsync(offsets, 0, (size_t)(2 * NN + 1) * sizeof(int), stream);
        hist_kernel<<<edge_blocks, 256, 0, stream>>>(dst, offsets);
        const int NB = (NN + 1023) / 1024;
        scanA<<<NB, 256, 0, stream>>>(offsets, blockSums, NN);
        scanB<<<1, 1024, 0, stream>>>(blockSums, NB);
        scanC<<<(NN + 255) / 256, 256, 0, stream>>>(offsets, blockSums, NN);
        scatter_sort<<<edge_blocks, 256, 0, stream>>>(src, dst, ew, W, offsets, cursor, sorted);

        const float* hin = x;
        float* houts[NLAYERS] = {bufA, out, bufA, out};
        for (int l = 0; l < NLAYERS; ++l) {
            gather1<<<node_blocks4, 256, 0, stream>>>(hin, sorted, offsets, degree, houts[l]);
            hin = houts[l];
        }
    }
}